// Round 6
// baseline (87.436 us; speedup 1.0000x reference)
//
#include <hip/hip_runtime.h>
#include <hip/hip_bf16.h>

#define B_DIM 4096
#define N_TOT 8192
// zn is pre-scaled by sqrt((1/0.07)*log2(e)) so MFMA output is already the
// exp2 exponent: S_scaled = S * (1/T) * log2(e).
#define SCALE 4.53981566f
#define LN2 0.69314718056f

typedef float f32x4 __attribute__((ext_vector_type(4)));
typedef __bf16 bf16x8 __attribute__((ext_vector_type(8)));

__device__ __forceinline__ float waveReduceSum(float v) {
#pragma unroll
    for (int off = 32; off > 0; off >>= 1) v += __shfl_xor(v, off);
    return v;
}

// async 16B global->LDS DMA: LDS dest = wave-uniform base + lane*16 (linear).
#define GLOAD16(gsrc, ldst)                                                      \
    __builtin_amdgcn_global_load_lds(                                            \
        (const __attribute__((address_space(1))) void*)(gsrc),                   \
        (__attribute__((address_space(3))) void*)(ldst), 16, 0, 0)

// Kernel 1: normalize rows into view-major order (i = v*B + b), pre-scaled by
// SCALE, emit bf16. Zeroes Z and lossOut (ws/out re-poisoned every launch).
__global__ void normalize_kernel(const float* __restrict__ feat,
                                 ushort* __restrict__ znb,
                                 float* __restrict__ Z,
                                 float* __restrict__ lossOut) {
    int gid = blockIdx.x * 256 + threadIdx.x;
    if (gid < N_TOT) Z[gid] = 0.f;
    if (gid == 0) lossOut[0] = 0.f;

    int row = blockIdx.x * 4 + (threadIdx.x >> 6);   // 2048 blocks * 4 waves
    int lane = threadIdx.x & 63;
    int b = row & (B_DIM - 1);
    int v = row >> 12;
    const float* src = feat + ((size_t)b * 2 + v) * 128;
    float2 x = *(const float2*)(src + lane * 2);
    float ss = waveReduceSum(x.x * x.x + x.y * x.y);
    float inv = SCALE / fmaxf(sqrtf(ss), 1e-8f);
    __hip_bfloat16 h0 = __float2bfloat16(x.x * inv);
    __hip_bfloat16 h1 = __float2bfloat16(x.y * inv);
    ushort2 u;
    u.x = *reinterpret_cast<ushort*>(&h0);
    u.y = *reinterpret_cast<ushort*>(&h1);
    *(ushort2*)(znb + (size_t)row * 128 + lane * 2) = u;
}

// Kernel 2: block = 128-row strip x 1024-col group, sweeping 8 tiles of 128
// cols. Waves in a 2x2 grid: each wave owns 64 rows x 64 cols -> A-panel
// (64 rows x K=128) lives in registers; per tile each wave reads only 16 KB
// of the B-tile from LDS (half the traffic of the 1x4-row layout). B-tiles
// double-buffered in LDS via global_load_lds (pre-swizzled source, rule #21):
//   stage(t+1 -> buf^1) ; compute(buf) ; vmcnt(0) ; barrier
// Row-sums of exp2(S_scaled) accumulate in registers; one shuffle-reduce +
// atomics per wave at sweep end. Self-term removed in finalize.
__global__ __launch_bounds__(256, 2) void sim_kernel(const ushort* __restrict__ znb,
                                                     float* __restrict__ Z) {
    __shared__ __align__(16) ushort Bs[2][128 * 128];

    const int bid = blockIdx.x;
    const int s = bid >> 3;                  // 64 row-strips
    const int g = bid & 7;                   // 8 col-groups (== XCD id under rr)
    const int r0 = s * 128, c0 = g * 1024;

    const int tid = threadIdx.x;
    const int lane = tid & 63;
    const int wid = tid >> 6;
    const int wr = wid >> 1, wc = wid & 1;   // 2x2 wave grid: 64 rows x 64 cols
    const int l16 = lane & 15;
    const int grp = lane >> 4;
    const char* zb = (const char*)znb;

    // A panel: wave owns rows r0 + wr*64 + m*16 + l16 (m=0..3), K-bytes kk*64+grp*16.
    bf16x8 a[4][4];
    {
        const char* pa = zb + (size_t)(r0 + wr * 64 + l16) * 256 + grp * 16;
#pragma unroll
        for (int m = 0; m < 4; ++m)
#pragma unroll
            for (int kk = 0; kk < 4; ++kk)
                a[m][kk] = *(const bf16x8*)(pa + m * 4096 + kk * 64);
    }

#define STAGE(t, buf)                                                            \
    do {                                                                         \
        const char* gB = zb + (size_t)(c0 + (t) * 128) * 256;                    \
        ushort* dst = Bs[buf] + (size_t)wid * 64 * 8;                            \
        int c = wid * 64 + lane;                                                 \
        _Pragma("unroll") for (int it = 0; it < 8; ++it) {                       \
            int row = c >> 4, ch = c & 15;                                       \
            int sch = ch ^ (row & 7);                                            \
            GLOAD16(gB + row * 256 + sch * 16, dst + it * 2048);                 \
            c += 256;                                                            \
        }                                                                        \
    } while (0)

    float esum[4][4];
#pragma unroll
    for (int m = 0; m < 4; ++m)
#pragma unroll
        for (int r = 0; r < 4; ++r) esum[m][r] = 0.f;

    STAGE(0, 0);
    asm volatile("s_waitcnt vmcnt(0)" ::: "memory");
    __syncthreads();

    const int sw = (l16 & 7) << 4;           // read-side swizzle (row&7 == l16&7)
    for (int t = 0; t < 8; ++t) {
        const int cur = t & 1;
        if (t < 7) STAGE(t + 1, cur ^ 1);

        const char* bsb = (const char*)Bs[cur];
        f32x4 acc[4][4] = {};
#pragma unroll
        for (int kk = 0; kk < 4; ++kk) {
            const int koff = (kk * 64 + grp * 16) ^ sw;
            bf16x8 bfr[4];
#pragma unroll
            for (int n = 0; n < 4; ++n)
                bfr[n] = *(const bf16x8*)(bsb + (wc * 64 + n * 16 + l16) * 256 + koff);
#pragma unroll
            for (int m = 0; m < 4; ++m)
#pragma unroll
                for (int n = 0; n < 4; ++n)
                    acc[m][n] = __builtin_amdgcn_mfma_f32_16x16x32_bf16(
                        a[m][kk], bfr[n], acc[m][n], 0, 0, 0);
        }
        // Epilogue: pure register row-sum accumulation (exponent pre-scaled).
#pragma unroll
        for (int m = 0; m < 4; ++m)
#pragma unroll
            for (int n = 0; n < 4; ++n)
#pragma unroll
                for (int r = 0; r < 4; ++r)
                    esum[m][r] += __builtin_amdgcn_exp2f(acc[m][n][r]);

        if (t < 7) asm volatile("s_waitcnt vmcnt(0)" ::: "memory");
        __syncthreads();
    }

    // Reduce across the 16 col-lanes; row = r0 + wr*64 + m*16 + grp*4 + r.
#pragma unroll
    for (int m = 0; m < 4; ++m)
#pragma unroll
        for (int r = 0; r < 4; ++r) {
            float v = esum[m][r];
            v += __shfl_xor(v, 1);
            v += __shfl_xor(v, 2);
            v += __shfl_xor(v, 4);
            v += __shfl_xor(v, 8);
            if (l16 == 0)
                atomicAdd(&Z[r0 + wr * 64 + m * 16 + grp * 4 + r], v);
        }
#undef STAGE
}

// Kernel 3: loss = (1/N) * sum_i [ log(Z_i - exp2(sd_i)) - pd_i * ln2 ],
// sd/pd recomputed in fp32 from the SAME scaled bf16 the MFMA consumed.
__global__ void finalize_kernel(const ushort* __restrict__ znb,
                                const float* __restrict__ Z,
                                float* __restrict__ lossOut) {
    int lane = threadIdx.x & 63;
    int wid = threadIdx.x >> 6;
    int gw = blockIdx.x * 4 + wid;           // 2048 waves, 4 rows each
    float acc = 0.f;
#pragma unroll
    for (int k = 0; k < 4; ++k) {
        int row = gw * 4 + k;
        int pos = (row + B_DIM) & (N_TOT - 1);
        ushort2 ua = *(const ushort2*)(znb + (size_t)row * 128 + lane * 2);
        ushort2 up = *(const ushort2*)(znb + (size_t)pos * 128 + lane * 2);
        float a0 = __uint_as_float((uint)ua.x << 16);
        float a1 = __uint_as_float((uint)ua.y << 16);
        float p0 = __uint_as_float((uint)up.x << 16);
        float p1 = __uint_as_float((uint)up.y << 16);
        float sd = waveReduceSum(a0 * a0 + a1 * a1);   // scaled self exponent
        float pd = waveReduceSum(a0 * p0 + a1 * p1);   // scaled positive exponent
        acc += logf(Z[row] - __builtin_amdgcn_exp2f(sd)) - pd * LN2;
    }
    __shared__ float part[4];
    if (lane == 0) part[wid] = acc;
    __syncthreads();
    if (threadIdx.x == 0) {
        float t = (part[0] + part[1] + part[2] + part[3]) * (1.0f / N_TOT);
        atomicAdd(lossOut, t);
    }
}

extern "C" void kernel_launch(void* const* d_in, const int* in_sizes, int n_in,
                              void* d_out, int out_size, void* d_ws, size_t ws_size,
                              hipStream_t stream) {
    const float* feat = (const float*)d_in[0];
    float* out = (float*)d_out;

    // ws layout: znb (2 MB) | Z (32 KB)
    ushort* znb = (ushort*)d_ws;
    float* Z = (float*)((char*)d_ws + (2u << 20));

    normalize_kernel<<<dim3(2048), dim3(256), 0, stream>>>(feat, znb, Z, out);
    sim_kernel<<<dim3(512), dim3(256), 0, stream>>>(znb, Z);
    finalize_kernel<<<dim3(512), dim3(256), 0, stream>>>(znb, Z, out);
}

// Round 7
// 85.962 us; speedup vs baseline: 1.0171x; 1.0171x over previous
//
#include <hip/hip_runtime.h>
#include <hip/hip_bf16.h>

#define B_DIM 4096
#define N_TOT 8192
// zn is pre-scaled by sqrt((1/0.07)*log2(e)) so MFMA output is already the
// exp2 exponent: S_scaled = S * (1/T) * log2(e).
#define SCALE 4.53981566f
#define LN2 0.69314718056f

typedef float f32x4 __attribute__((ext_vector_type(4)));
typedef __bf16 bf16x8 __attribute__((ext_vector_type(8)));

__device__ __forceinline__ float waveReduceSum(float v) {
#pragma unroll
    for (int off = 32; off > 0; off >>= 1) v += __shfl_xor(v, off);
    return v;
}

// async 16B global->LDS DMA: LDS dest = wave-uniform base + lane*16 (linear).
#define GLOAD16(gsrc, ldst)                                                      \
    __builtin_amdgcn_global_load_lds(                                            \
        (const __attribute__((address_space(1))) void*)(gsrc),                   \
        (__attribute__((address_space(3))) void*)(ldst), 16, 0, 0)

// Kernel 1: normalize rows into view-major order (i = v*B + b), pre-scaled by
// SCALE, emit bf16. Zeroes Z and lossOut (ws/out re-poisoned every launch).
__global__ void normalize_kernel(const float* __restrict__ feat,
                                 ushort* __restrict__ znb,
                                 float* __restrict__ Z,
                                 float* __restrict__ lossOut) {
    int gid = blockIdx.x * 256 + threadIdx.x;
    if (gid < N_TOT) Z[gid] = 0.f;
    if (gid == 0) lossOut[0] = 0.f;

    int row = blockIdx.x * 4 + (threadIdx.x >> 6);   // 2048 blocks * 4 waves
    int lane = threadIdx.x & 63;
    int b = row & (B_DIM - 1);
    int v = row >> 12;
    const float* src = feat + ((size_t)b * 2 + v) * 128;
    float2 x = *(const float2*)(src + lane * 2);
    float ss = waveReduceSum(x.x * x.x + x.y * x.y);
    float inv = SCALE / fmaxf(sqrtf(ss), 1e-8f);
    __hip_bfloat16 h0 = __float2bfloat16(x.x * inv);
    __hip_bfloat16 h1 = __float2bfloat16(x.y * inv);
    ushort2 u;
    u.x = *reinterpret_cast<ushort*>(&h0);
    u.y = *reinterpret_cast<ushort*>(&h1);
    *(ushort2*)(znb + (size_t)row * 128 + lane * 2) = u;
}

// Kernel 2: block = 128-row strip x 1024-col group, sweeping 8 tiles of 128
// cols. STAGGERED sweep: block at row-strip s starts its sweep at tile (s&7),
// so the 64 blocks sharing a col-group hit 8 DIFFERENT B-tiles at any instant
// (8-way same-line L2 sharing instead of 64-way storm). Waves 2x2: each wave
// 64 rows x 64 cols, A-panel in registers, B double-buffered in LDS via
// global_load_lds (pre-swizzled source). setprio(1) around the MFMA+exp
// cluster. Self-term removed in finalize.
__global__ __launch_bounds__(256, 2) void sim_kernel(const ushort* __restrict__ znb,
                                                     float* __restrict__ Z) {
    __shared__ __align__(16) ushort Bs[2][128 * 128];

    const int bid = blockIdx.x;
    const int s = bid >> 3;                  // 64 row-strips
    const int g = bid & 7;                   // 8 col-groups (== XCD id under rr)
    const int r0 = s * 128, c0 = g * 1024;
    const int ph0 = s & 7;                   // stagger offset within the sweep

    const int tid = threadIdx.x;
    const int lane = tid & 63;
    const int wid = tid >> 6;
    const int wr = wid >> 1, wc = wid & 1;   // 2x2 wave grid: 64 rows x 64 cols
    const int l16 = lane & 15;
    const int grp = lane >> 4;
    const char* zb = (const char*)znb;

    // A panel: wave owns rows r0 + wr*64 + m*16 + l16 (m=0..3), K-bytes kk*64+grp*16.
    bf16x8 a[4][4];
    {
        const char* pa = zb + (size_t)(r0 + wr * 64 + l16) * 256 + grp * 16;
#pragma unroll
        for (int m = 0; m < 4; ++m)
#pragma unroll
            for (int kk = 0; kk < 4; ++kk)
                a[m][kk] = *(const bf16x8*)(pa + m * 4096 + kk * 64);
    }

#define STAGE(tile, buf)                                                         \
    do {                                                                         \
        const char* gB = zb + (size_t)(c0 + (tile) * 128) * 256;                 \
        ushort* dst = Bs[buf] + (size_t)wid * 64 * 8;                            \
        int c = wid * 64 + lane;                                                 \
        _Pragma("unroll") for (int it = 0; it < 8; ++it) {                       \
            int row = c >> 4, ch = c & 15;                                       \
            int sch = ch ^ (row & 7);                                            \
            GLOAD16(gB + row * 256 + sch * 16, dst + it * 2048);                 \
            c += 256;                                                            \
        }                                                                        \
    } while (0)

    float esum[4][4];
#pragma unroll
    for (int m = 0; m < 4; ++m)
#pragma unroll
        for (int r = 0; r < 4; ++r) esum[m][r] = 0.f;

    STAGE(ph0, 0);
    asm volatile("s_waitcnt vmcnt(0)" ::: "memory");
    __syncthreads();

    const int sw = (l16 & 7) << 4;           // read-side swizzle (row&7 == l16&7)
    for (int t = 0; t < 8; ++t) {
        const int cur = t & 1;
        if (t < 7) STAGE((t + 1 + ph0) & 7, cur ^ 1);

        __builtin_amdgcn_s_setprio(1);
        const char* bsb = (const char*)Bs[cur];
        f32x4 acc[4][4] = {};
#pragma unroll
        for (int kk = 0; kk < 4; ++kk) {
            const int koff = (kk * 64 + grp * 16) ^ sw;
            bf16x8 bfr[4];
#pragma unroll
            for (int n = 0; n < 4; ++n)
                bfr[n] = *(const bf16x8*)(bsb + (wc * 64 + n * 16 + l16) * 256 + koff);
#pragma unroll
            for (int m = 0; m < 4; ++m)
#pragma unroll
                for (int n = 0; n < 4; ++n)
                    acc[m][n] = __builtin_amdgcn_mfma_f32_16x16x32_bf16(
                        a[m][kk], bfr[n], acc[m][n], 0, 0, 0);
        }
        // Epilogue: pure register row-sum accumulation (exponent pre-scaled).
#pragma unroll
        for (int m = 0; m < 4; ++m)
#pragma unroll
            for (int n = 0; n < 4; ++n)
#pragma unroll
                for (int r = 0; r < 4; ++r)
                    esum[m][r] += __builtin_amdgcn_exp2f(acc[m][n][r]);
        __builtin_amdgcn_s_setprio(0);

        if (t < 7) asm volatile("s_waitcnt vmcnt(0)" ::: "memory");
        __syncthreads();
    }

    // Reduce across the 16 col-lanes; row = r0 + wr*64 + m*16 + grp*4 + r.
#pragma unroll
    for (int m = 0; m < 4; ++m)
#pragma unroll
        for (int r = 0; r < 4; ++r) {
            float v = esum[m][r];
            v += __shfl_xor(v, 1);
            v += __shfl_xor(v, 2);
            v += __shfl_xor(v, 4);
            v += __shfl_xor(v, 8);
            if (l16 == 0)
                atomicAdd(&Z[r0 + wr * 64 + m * 16 + grp * 4 + r], v);
        }
#undef STAGE
}

// Kernel 3: loss = (1/N) * sum_i [ log(Z_i - exp2(sd_i)) - pd_i * ln2 ],
// sd/pd recomputed in fp32 from the SAME scaled bf16 the MFMA consumed.
__global__ void finalize_kernel(const ushort* __restrict__ znb,
                                const float* __restrict__ Z,
                                float* __restrict__ lossOut) {
    int lane = threadIdx.x & 63;
    int wid = threadIdx.x >> 6;
    int gw = blockIdx.x * 4 + wid;           // 2048 waves, 4 rows each
    float acc = 0.f;
#pragma unroll
    for (int k = 0; k < 4; ++k) {
        int row = gw * 4 + k;
        int pos = (row + B_DIM) & (N_TOT - 1);
        ushort2 ua = *(const ushort2*)(znb + (size_t)row * 128 + lane * 2);
        ushort2 up = *(const ushort2*)(znb + (size_t)pos * 128 + lane * 2);
        float a0 = __uint_as_float((uint)ua.x << 16);
        float a1 = __uint_as_float((uint)ua.y << 16);
        float p0 = __uint_as_float((uint)up.x << 16);
        float p1 = __uint_as_float((uint)up.y << 16);
        float sd = waveReduceSum(a0 * a0 + a1 * a1);   // scaled self exponent
        float pd = waveReduceSum(a0 * p0 + a1 * p1);   // scaled positive exponent
        acc += logf(Z[row] - __builtin_amdgcn_exp2f(sd)) - pd * LN2;
    }
    __shared__ float part[4];
    if (lane == 0) part[wid] = acc;
    __syncthreads();
    if (threadIdx.x == 0) {
        float t = (part[0] + part[1] + part[2] + part[3]) * (1.0f / N_TOT);
        atomicAdd(lossOut, t);
    }
}

extern "C" void kernel_launch(void* const* d_in, const int* in_sizes, int n_in,
                              void* d_out, int out_size, void* d_ws, size_t ws_size,
                              hipStream_t stream) {
    const float* feat = (const float*)d_in[0];
    float* out = (float*)d_out;

    // ws layout: znb (2 MB) | Z (32 KB)
    ushort* znb = (ushort*)d_ws;
    float* Z = (float*)((char*)d_ws + (2u << 20));

    normalize_kernel<<<dim3(2048), dim3(256), 0, stream>>>(feat, znb, Z, out);
    sim_kernel<<<dim3(512), dim3(256), 0, stream>>>(znb, Z);
    finalize_kernel<<<dim3(512), dim3(256), 0, stream>>>(znb, Z, out);
}